// Round 1
// baseline (836.145 us; speedup 1.0000x reference)
//
#include <hip/hip_runtime.h>

#define N_NODES 50000
#define N_EDGES 640000
#define F_IN 20
#define H 128
#define G_GRAPHS 100
#define OUT_C 2

// ---- edge pass 1: aggregate x over edges, and compute in-degree ----
// one thread per (edge, feature) pair; f==0 thread also bumps degree.
__global__ __launch_bounds__(256) void edge_agg1(
    const int* __restrict__ src, const int* __restrict__ dst,
    const float* __restrict__ x, float* __restrict__ agg1,
    float* __restrict__ deg) {
  int tid = blockIdx.x * 256 + threadIdx.x;
  if (tid >= N_EDGES * F_IN) return;
  int e = tid / F_IN;
  int f = tid - e * F_IN;
  int s = src[e], d = dst[e];
  atomicAdd(&agg1[d * F_IN + f], x[s * F_IN + f]);
  if (f == 0) atomicAdd(&deg[d], 1.0f);
}

// ---- conv1: h1 = relu(W1l @ mean1 + b1l + W1r @ x) ; one node per block ----
__global__ __launch_bounds__(128) void conv1_kernel(
    const float* __restrict__ x, const float* __restrict__ agg1,
    const float* __restrict__ deg,
    const float* __restrict__ W1l, const float* __restrict__ b1l,
    const float* __restrict__ W1r, float* __restrict__ h1) {
  int i = blockIdx.x;
  int t = threadIdx.x;
  __shared__ float sm[F_IN];
  __shared__ float sx[F_IN];
  if (t < F_IN) {
    float dg = fmaxf(deg[i], 1.0f);
    sm[t] = agg1[i * F_IN + t] / dg;
    sx[t] = x[i * F_IN + t];
  }
  __syncthreads();
  float acc = b1l[t];
#pragma unroll
  for (int k = 0; k < F_IN; ++k)
    acc += W1l[t * F_IN + k] * sm[k] + W1r[t * F_IN + k] * sx[k];
  h1[i * H + t] = fmaxf(acc, 0.0f);
}

// ---- edge pass 2: agg2[dst] += h1[src], thread per (edge, feature) ----
__global__ __launch_bounds__(256) void edge_agg2(
    const int* __restrict__ src, const int* __restrict__ dst,
    const float* __restrict__ h1, float* __restrict__ agg2) {
  int tid = blockIdx.x * 256 + threadIdx.x;  // E*H = 81,920,000 < 2^31
  int e = tid >> 7;
  int f = tid & 127;
  atomicAdd(&agg2[dst[e] * H + f], h1[src[e] * H + f]);
}

// ---- transpose a 128x128 weight so conv2 reads are coalesced ----
__global__ __launch_bounds__(128) void transpose128(
    const float* __restrict__ W, float* __restrict__ WT) {
  int k = blockIdx.x;
  int t = threadIdx.x;
  WT[k * H + t] = W[t * H + k];
}

// ---- conv2 + relu + global mean-pool accumulation, 16 nodes per block ----
__global__ __launch_bounds__(128) void conv2_pool(
    const float* __restrict__ h1, const float* __restrict__ agg2,
    const float* __restrict__ deg,
    const float* __restrict__ W2lT, const float* __restrict__ b2l,
    const float* __restrict__ W2rT,
    const int* __restrict__ batch,
    float* __restrict__ gsum, float* __restrict__ gcnt) {
  const int NODES = 16;
  int base = blockIdx.x * NODES;
  int t = threadIdx.x;
  __shared__ float feat[NODES][2 * H];  // [n][k<128: mean2 | k>=128: h1]
#pragma unroll
  for (int j = 0; j < 2 * NODES; ++j) {
    int l = j * H + t;  // 0 .. 16*256-1
    int n = l >> 8;
    int k = l & 255;
    int node = base + n;
    float v;
    if (k < H)
      v = agg2[node * H + k] / fmaxf(deg[node], 1.0f);
    else
      v = h1[node * H + (k - H)];
    feat[n][k] = v;
  }
  __syncthreads();
  float b = b2l[t];
  float acc[NODES];
#pragma unroll
  for (int n = 0; n < NODES; ++n) acc[n] = b;
  for (int k = 0; k < H; ++k) {
    float wl = W2lT[k * H + t];
    float wr = W2rT[k * H + t];
#pragma unroll
    for (int n = 0; n < NODES; ++n)
      acc[n] += wl * feat[n][k] + wr * feat[n][H + k];
  }
#pragma unroll
  for (int n = 0; n < NODES; ++n) {
    int node = base + n;
    float v = fmaxf(acc[n], 0.0f);
    atomicAdd(&gsum[batch[node] * H + t], v);
  }
  if (t == 0) {
#pragma unroll
    for (int n = 0; n < NODES; ++n) atomicAdd(&gcnt[batch[base + n]], 1.0f);
  }
}

// ---- final: out = (gsum/gcnt) @ Wlin.T + blin ----
__global__ __launch_bounds__(256) void final_lin(
    const float* __restrict__ gsum, const float* __restrict__ gcnt,
    const float* __restrict__ Wlin, const float* __restrict__ blin,
    float* __restrict__ out) {
  int t = blockIdx.x * 256 + threadIdx.x;
  if (t >= G_GRAPHS * OUT_C) return;
  int g = t / OUT_C, o = t - g * OUT_C;
  float inv = 1.0f / fmaxf(gcnt[g], 1.0f);
  float acc = blin[o];
#pragma unroll 16
  for (int k = 0; k < H; ++k)
    acc += (gsum[g * H + k] * inv) * Wlin[o * H + k];
  out[t] = acc;
}

extern "C" void kernel_launch(void* const* d_in, const int* in_sizes, int n_in,
                              void* d_out, int out_size, void* d_ws, size_t ws_size,
                              hipStream_t stream) {
  const float* x    = (const float*)d_in[0];
  const int*   ei   = (const int*)d_in[1];
  const int*   batch= (const int*)d_in[2];
  const float* W1l  = (const float*)d_in[3];
  const float* b1l  = (const float*)d_in[4];
  const float* W1r  = (const float*)d_in[5];
  const float* W2l  = (const float*)d_in[6];
  const float* b2l  = (const float*)d_in[7];
  const float* W2r  = (const float*)d_in[8];
  const float* Wlin = (const float*)d_in[9];
  const float* blin = (const float*)d_in[10];
  float* out = (float*)d_out;

  const int* src = ei;
  const int* dst = ei + N_EDGES;

  float* ws   = (float*)d_ws;
  float* deg  = ws;                       // N
  float* gcnt = deg + N_NODES;            // G
  float* gsum = gcnt + G_GRAPHS;          // G*H
  float* agg1 = gsum + G_GRAPHS * H;      // N*F_IN
  float* agg2 = agg1 + N_NODES * F_IN;    // N*H
  float* h1   = agg2 + (size_t)N_NODES * H;  // N*H
  float* W2lT = h1 + (size_t)N_NODES * H;    // H*H
  float* W2rT = W2lT + H * H;                // H*H

  size_t zero_floats = (size_t)N_NODES + G_GRAPHS + G_GRAPHS * H +
                       (size_t)N_NODES * F_IN + (size_t)N_NODES * H;
  hipMemsetAsync(ws, 0, zero_floats * sizeof(float), stream);

  transpose128<<<H, H, 0, stream>>>(W2l, W2lT);
  transpose128<<<H, H, 0, stream>>>(W2r, W2rT);
  edge_agg1<<<(N_EDGES * F_IN + 255) / 256, 256, 0, stream>>>(src, dst, x, agg1, deg);
  conv1_kernel<<<N_NODES, H, 0, stream>>>(x, agg1, deg, W1l, b1l, W1r, h1);
  edge_agg2<<<(N_EDGES * H) / 256, 256, 0, stream>>>(src, dst, h1, agg2);
  conv2_pool<<<N_NODES / 16, H, 0, stream>>>(h1, agg2, deg, W2lT, b2l, W2rT, batch, gsum, gcnt);
  final_lin<<<1, 256, 0, stream>>>(gsum, gcnt, Wlin, blin, out);
}

// Round 2
// 628.519 us; speedup vs baseline: 1.3303x; 1.3303x over previous
//
#include <hip/hip_runtime.h>

#define N_NODES 50000
#define N_EDGES 640000
#define F_IN 20
#define H 128
#define G_GRAPHS 100
#define OUT_C 2
#define TILE_N 64   // nodes per conv2 block

// ---- edge pass 1: aggregate x over edges, and compute in-degree ----
__global__ __launch_bounds__(256) void edge_agg1(
    const int* __restrict__ src, const int* __restrict__ dst,
    const float* __restrict__ x, float* __restrict__ agg1,
    float* __restrict__ deg) {
  int tid = blockIdx.x * 256 + threadIdx.x;
  if (tid >= N_EDGES * F_IN) return;
  int e = tid / F_IN;
  int f = tid - e * F_IN;
  int s = src[e], d = dst[e];
  atomicAdd(&agg1[d * F_IN + f], x[s * F_IN + f]);
  if (f == 0) atomicAdd(&deg[d], 1.0f);
}

// ---- conv1: h1 = relu(W1l @ mean1 + b1l + W1r @ x) ; one node per block ----
__global__ __launch_bounds__(128) void conv1_kernel(
    const float* __restrict__ x, const float* __restrict__ agg1,
    const float* __restrict__ deg,
    const float* __restrict__ W1l, const float* __restrict__ b1l,
    const float* __restrict__ W1r, float* __restrict__ h1) {
  int i = blockIdx.x;
  int t = threadIdx.x;
  __shared__ float sm[F_IN];
  __shared__ float sx[F_IN];
  if (t < F_IN) {
    float dg = fmaxf(deg[i], 1.0f);
    sm[t] = agg1[i * F_IN + t] / dg;
    sx[t] = x[i * F_IN + t];
  }
  __syncthreads();
  float acc = b1l[t];
#pragma unroll
  for (int k = 0; k < F_IN; ++k)
    acc += W1l[t * F_IN + k] * sm[k] + W1r[t * F_IN + k] * sx[k];
  h1[i * H + t] = fmaxf(acc, 0.0f);
}

// ---- edge pass 2: agg2[dst] += h1[src], thread per (edge, feature) ----
__global__ __launch_bounds__(256) void edge_agg2(
    const int* __restrict__ src, const int* __restrict__ dst,
    const float* __restrict__ h1, float* __restrict__ agg2) {
  int tid = blockIdx.x * 256 + threadIdx.x;  // E*H = 81,920,000 < 2^31
  int e = tid >> 7;
  int f = tid & 127;
  atomicAdd(&agg2[dst[e] * H + f], h1[src[e] * H + f]);
}

// ---- build Wcat[256][128]: rows 0..127 = W2l.T, rows 128..255 = W2r.T ----
__global__ __launch_bounds__(128) void build_wcat(
    const float* __restrict__ W2l, const float* __restrict__ W2r,
    float* __restrict__ Wcat) {
  int k = blockIdx.x;   // 0..255
  int t = threadIdx.x;  // 0..127 (output col)
  Wcat[k * H + t] = (k < H) ? W2l[t * H + k] : W2r[t * H + (k - H)];
}

// ---- conv2 + relu + pool: register-tiled GEMM, 64 nodes/block ----
// C[64][128] = A[64][256] @ Wcat[256][128]; A = [mean2 | h1]
// 256 threads: cg = t&31 (cols cg*4..+3), ng = t>>5 (nodes ng*8..+7)
__global__ __launch_bounds__(256) void conv2_pool(
    const float* __restrict__ h1, const float* __restrict__ agg2,
    const float* __restrict__ deg, const float* __restrict__ Wcat,
    const float* __restrict__ b2l, const int* __restrict__ batch,
    float* __restrict__ gsum, float* __restrict__ gcnt) {
  __shared__ float a[TILE_N * 256];  // 64 KB; reused as 64x128 out tile
  int t = threadIdx.x;
  int base = blockIdx.x * TILE_N;
  int nvalid = min(TILE_N, N_NODES - base);

  // load A tile: 16384 floats, 64/thread as float4, fully coalesced rows
#pragma unroll
  for (int chunk = 0; chunk < 16; ++chunk) {
    int idx = chunk * 1024 + t * 4;
    int row = idx >> 8;
    int col = idx & 255;
    int node = base + row;
    float4 v = make_float4(0.f, 0.f, 0.f, 0.f);
    if (node < N_NODES) {
      if (col < H) {
        v = *(const float4*)(agg2 + (size_t)node * H + col);
        float invd = 1.0f / fmaxf(deg[node], 1.0f);
        v.x *= invd; v.y *= invd; v.z *= invd; v.w *= invd;
      } else {
        v = *(const float4*)(h1 + (size_t)node * H + (col - H));
      }
    }
    *(float4*)(a + idx) = v;
  }
  __syncthreads();

  int cg = t & 31, ng = t >> 5;
  float4 bb = *(const float4*)(b2l + cg * 4);
  float4 acc[8];
#pragma unroll
  for (int n = 0; n < 8; ++n) acc[n] = bb;

  const float4* __restrict__ WcatV = (const float4*)Wcat;
  const float4* aV = (const float4*)a;
#pragma unroll 4
  for (int k4 = 0; k4 < 64; ++k4) {
    float4 w0 = WcatV[(k4 * 4 + 0) * 32 + cg];
    float4 w1 = WcatV[(k4 * 4 + 1) * 32 + cg];
    float4 w2 = WcatV[(k4 * 4 + 2) * 32 + cg];
    float4 w3 = WcatV[(k4 * 4 + 3) * 32 + cg];
#pragma unroll
    for (int n = 0; n < 8; ++n) {
      float4 av = aV[(ng * 8 + n) * 64 + k4];
      acc[n].x += av.x * w0.x + av.y * w1.x + av.z * w2.x + av.w * w3.x;
      acc[n].y += av.x * w0.y + av.y * w1.y + av.z * w2.y + av.w * w3.y;
      acc[n].z += av.x * w0.z + av.y * w1.z + av.z * w2.z + av.w * w3.z;
      acc[n].w += av.x * w0.w + av.y * w1.w + av.z * w2.w + av.w * w3.w;
    }
  }
  __syncthreads();  // done reading A tile; reuse as out tile

  // write relu'd outputs to LDS out tile [64][128]
#pragma unroll
  for (int n = 0; n < 8; ++n) {
    float4 r;
    r.x = fmaxf(acc[n].x, 0.f);
    r.y = fmaxf(acc[n].y, 0.f);
    r.z = fmaxf(acc[n].z, 0.f);
    r.w = fmaxf(acc[n].w, 0.f);
    *(float4*)(a + (ng * 8 + n) * H + cg * 4) = r;
  }
  __syncthreads();

  // segmented pool: batch is sorted, so this block spans ~1-2 graphs
  if (t < H) {
    int cur = batch[base];
    float s = 0.f;
#pragma unroll 8
    for (int n = 0; n < nvalid; ++n) {
      int g = batch[base + n];
      if (g != cur) {
        atomicAdd(&gsum[cur * H + t], s);
        s = 0.f;
        cur = g;
      }
      s += a[n * H + t];
    }
    atomicAdd(&gsum[cur * H + t], s);
  } else if (t == H) {
    int cur = batch[base];
    float c = 0.f;
    for (int n = 0; n < nvalid; ++n) {
      int g = batch[base + n];
      if (g != cur) {
        atomicAdd(&gcnt[cur], c);
        c = 0.f;
        cur = g;
      }
      c += 1.0f;
    }
    atomicAdd(&gcnt[cur], c);
  }
}

// ---- final: out = (gsum/gcnt) @ Wlin.T + blin ----
__global__ __launch_bounds__(256) void final_lin(
    const float* __restrict__ gsum, const float* __restrict__ gcnt,
    const float* __restrict__ Wlin, const float* __restrict__ blin,
    float* __restrict__ out) {
  int t = blockIdx.x * 256 + threadIdx.x;
  if (t >= G_GRAPHS * OUT_C) return;
  int g = t / OUT_C, o = t - g * OUT_C;
  float inv = 1.0f / fmaxf(gcnt[g], 1.0f);
  float acc = blin[o];
#pragma unroll 16
  for (int k = 0; k < H; ++k)
    acc += (gsum[g * H + k] * inv) * Wlin[o * H + k];
  out[t] = acc;
}

extern "C" void kernel_launch(void* const* d_in, const int* in_sizes, int n_in,
                              void* d_out, int out_size, void* d_ws, size_t ws_size,
                              hipStream_t stream) {
  const float* x    = (const float*)d_in[0];
  const int*   ei   = (const int*)d_in[1];
  const int*   batch= (const int*)d_in[2];
  const float* W1l  = (const float*)d_in[3];
  const float* b1l  = (const float*)d_in[4];
  const float* W1r  = (const float*)d_in[5];
  const float* W2l  = (const float*)d_in[6];
  const float* b2l  = (const float*)d_in[7];
  const float* W2r  = (const float*)d_in[8];
  const float* Wlin = (const float*)d_in[9];
  const float* blin = (const float*)d_in[10];
  float* out = (float*)d_out;

  const int* src = ei;
  const int* dst = ei + N_EDGES;

  float* ws   = (float*)d_ws;
  float* deg  = ws;                          // N
  float* gcnt = deg + N_NODES;               // G
  float* gsum = gcnt + G_GRAPHS;             // G*H
  float* agg1 = gsum + G_GRAPHS * H;         // N*F_IN
  float* agg2 = agg1 + N_NODES * F_IN;       // N*H
  float* h1   = agg2 + (size_t)N_NODES * H;  // N*H
  float* Wcat = h1 + (size_t)N_NODES * H;    // 256*H

  size_t zero_floats = (size_t)N_NODES + G_GRAPHS + G_GRAPHS * H +
                       (size_t)N_NODES * F_IN + (size_t)N_NODES * H;
  hipMemsetAsync(ws, 0, zero_floats * sizeof(float), stream);

  build_wcat<<<2 * H, H, 0, stream>>>(W2l, W2r, Wcat);
  edge_agg1<<<(N_EDGES * F_IN + 255) / 256, 256, 0, stream>>>(src, dst, x, agg1, deg);
  conv1_kernel<<<N_NODES, H, 0, stream>>>(x, agg1, deg, W1l, b1l, W1r, h1);
  edge_agg2<<<(N_EDGES * H) / 256, 256, 0, stream>>>(src, dst, h1, agg2);
  conv2_pool<<<(N_NODES + TILE_N - 1) / TILE_N, 256, 0, stream>>>(
      h1, agg2, deg, Wcat, b2l, batch, gsum, gcnt);
  final_lin<<<1, 256, 0, stream>>>(gsum, gcnt, Wlin, blin, out);
}

// Round 3
// 401.562 us; speedup vs baseline: 2.0822x; 1.5652x over previous
//
#include <hip/hip_runtime.h>

#define N_NODES 50000
#define N_EDGES 640000
#define F_IN 20
#define H 128
#define G_GRAPHS 100
#define OUT_C 2
#define TILE_N 64

// ---- count in-degree (int) ----
__global__ __launch_bounds__(256) void count_deg(
    const int* __restrict__ dst, int* __restrict__ ideg) {
  int e = blockIdx.x * 256 + threadIdx.x;
  if (e < N_EDGES) atomicAdd(&ideg[dst[e]], 1);
}

// ---- single-block exclusive scan: off[i], cursor[i] = prefix; off[N] = E ----
__global__ __launch_bounds__(1024) void scan_offsets(
    const int* __restrict__ ideg, int* __restrict__ off, int* __restrict__ cursor) {
  __shared__ int part[1024];
  int t = threadIdx.x;
  const int CHUNK = (N_NODES + 1023) / 1024;  // 49
  int beg = t * CHUNK, end = min(beg + CHUNK, N_NODES);
  int s = 0;
  for (int i = beg; i < end; ++i) s += ideg[i];
  part[t] = s;
  __syncthreads();
  for (int d = 1; d < 1024; d <<= 1) {
    int v = (t >= d) ? part[t - d] : 0;
    __syncthreads();
    part[t] += v;
    __syncthreads();
  }
  int run = (t == 0) ? 0 : part[t - 1];
  for (int i = beg; i < end; ++i) {
    off[i] = run;
    cursor[i] = run;
    run += ideg[i];
  }
  if (t == 1023) off[N_NODES] = run;
}

// ---- scatter edges into dst-sorted order ----
__global__ __launch_bounds__(256) void scatter_edges(
    const int* __restrict__ src, const int* __restrict__ dst,
    int* __restrict__ cursor, int* __restrict__ ssrc) {
  int e = blockIdx.x * 256 + threadIdx.x;
  if (e < N_EDGES) {
    int pos = atomicAdd(&cursor[dst[e]], 1);
    ssrc[pos] = src[e];
  }
}

// ---- hop-1 mean aggregation via CSR: one wave per node, 3 edges per pass ----
__global__ __launch_bounds__(256) void csr_agg1(
    const int* __restrict__ off, const int* __restrict__ ssrc,
    const float* __restrict__ x, float* __restrict__ mean1) {
  int node = blockIdx.x * 4 + (threadIdx.x >> 6);
  if (node >= N_NODES) return;
  int lane = threadIdx.x & 63;
  int beg = off[node], end = off[node + 1];
  int j = lane / F_IN;          // 0..3
  int f = lane - j * F_IN;      // 0..19
  float acc = 0.f;
  if (lane < 60) {
    for (int e = beg + j; e < end; e += 3)
      acc += x[(size_t)ssrc[e] * F_IN + f];
  }
  float s = acc + __shfl(acc, lane + 20, 64) + __shfl(acc, lane + 40, 64);
  if (lane < F_IN) {
    float invd = 1.f / fmaxf((float)(end - beg), 1.f);
    mean1[(size_t)node * F_IN + lane] = s * invd;
  }
}

// ---- Wcat1[40][128]: rows 0..19 = W1l.T, rows 20..39 = W1r.T ----
__global__ __launch_bounds__(128) void build_wcat1(
    const float* __restrict__ W1l, const float* __restrict__ W1r,
    float* __restrict__ Wcat1) {
  int k = blockIdx.x;   // 0..39
  int t = threadIdx.x;  // 0..127
  Wcat1[k * H + t] = (k < F_IN) ? W1l[t * F_IN + k] : W1r[t * F_IN + (k - F_IN)];
}

// ---- conv1: register-tiled, 64 nodes/block; A=[mean1|x] (64x40) ----
__global__ __launch_bounds__(256) void conv1_tiled(
    const float* __restrict__ mean1, const float* __restrict__ x,
    const float* __restrict__ Wcat1, const float* __restrict__ b1l,
    float* __restrict__ h1) {
  __shared__ float a[TILE_N * 2 * F_IN];  // 64x40 = 10 KB
  int t = threadIdx.x;
  int base = blockIdx.x * TILE_N;
#pragma unroll
  for (int j = 0; j < 10; ++j) {
    int idx = j * 256 + t;
    int row = idx / (2 * F_IN);
    int col = idx - row * (2 * F_IN);
    int node = base + row;
    float v = 0.f;
    if (node < N_NODES)
      v = (col < F_IN) ? mean1[(size_t)node * F_IN + col]
                       : x[(size_t)node * F_IN + (col - F_IN)];
    a[idx] = v;
  }
  __syncthreads();
  int cg = t & 31, ng = t >> 5;
  float4 bb = *(const float4*)(b1l + cg * 4);
  float4 acc[8];
#pragma unroll
  for (int n = 0; n < 8; ++n) acc[n] = bb;
  const float4* __restrict__ WV = (const float4*)Wcat1;
#pragma unroll 8
  for (int k = 0; k < 2 * F_IN; ++k) {
    float4 w = WV[k * 32 + cg];
#pragma unroll
    for (int n = 0; n < 8; ++n) {
      float av = a[(ng * 8 + n) * (2 * F_IN) + k];
      acc[n].x += av * w.x;
      acc[n].y += av * w.y;
      acc[n].z += av * w.z;
      acc[n].w += av * w.w;
    }
  }
#pragma unroll
  for (int n = 0; n < 8; ++n) {
    int node = base + ng * 8 + n;
    if (node < N_NODES) {
      float4 r;
      r.x = fmaxf(acc[n].x, 0.f);
      r.y = fmaxf(acc[n].y, 0.f);
      r.z = fmaxf(acc[n].z, 0.f);
      r.w = fmaxf(acc[n].w, 0.f);
      *(float4*)(h1 + (size_t)node * H + cg * 4) = r;
    }
  }
}

// ---- hop-2 mean aggregation via CSR: one wave per node, float2/lane ----
__global__ __launch_bounds__(256) void csr_agg2(
    const int* __restrict__ off, const int* __restrict__ ssrc,
    const float* __restrict__ h1, float* __restrict__ mean2) {
  int node = blockIdx.x * 4 + (threadIdx.x >> 6);
  if (node >= N_NODES) return;
  int lane = threadIdx.x & 63;
  int beg = off[node], end = off[node + 1];
  float ax = 0.f, ay = 0.f;
  int e = beg;
  for (; e + 3 < end; e += 4) {
    int s0 = ssrc[e], s1 = ssrc[e + 1], s2 = ssrc[e + 2], s3 = ssrc[e + 3];
    float2 v0 = *(const float2*)(h1 + (size_t)s0 * H + lane * 2);
    float2 v1 = *(const float2*)(h1 + (size_t)s1 * H + lane * 2);
    float2 v2 = *(const float2*)(h1 + (size_t)s2 * H + lane * 2);
    float2 v3 = *(const float2*)(h1 + (size_t)s3 * H + lane * 2);
    ax += v0.x + v1.x + v2.x + v3.x;
    ay += v0.y + v1.y + v2.y + v3.y;
  }
  for (; e < end; ++e) {
    float2 v = *(const float2*)(h1 + (size_t)ssrc[e] * H + lane * 2);
    ax += v.x;
    ay += v.y;
  }
  float invd = 1.f / fmaxf((float)(end - beg), 1.f);
  float2 r;
  r.x = ax * invd;
  r.y = ay * invd;
  *(float2*)(mean2 + (size_t)node * H + lane * 2) = r;
}

// ---- Wcat2[256][128]: rows 0..127 = W2l.T, rows 128..255 = W2r.T ----
__global__ __launch_bounds__(128) void build_wcat2(
    const float* __restrict__ W2l, const float* __restrict__ W2r,
    float* __restrict__ Wcat2) {
  int k = blockIdx.x;   // 0..255
  int t = threadIdx.x;  // 0..127
  Wcat2[k * H + t] = (k < H) ? W2l[t * H + k] : W2r[t * H + (k - H)];
}

// ---- conv2 + relu + pool: register-tiled GEMM, 64 nodes/block ----
__global__ __launch_bounds__(256) void conv2_pool(
    const float* __restrict__ h1, const float* __restrict__ mean2,
    const float* __restrict__ Wcat2, const float* __restrict__ b2l,
    const int* __restrict__ batch,
    float* __restrict__ gsum, float* __restrict__ gcnt) {
  __shared__ float a[TILE_N * 256];  // 64 KB; reused as 64x128 out tile
  int t = threadIdx.x;
  int base = blockIdx.x * TILE_N;
  int nvalid = min(TILE_N, N_NODES - base);

#pragma unroll
  for (int chunk = 0; chunk < 16; ++chunk) {
    int idx = chunk * 1024 + t * 4;
    int row = idx >> 8;
    int col = idx & 255;
    int node = base + row;
    float4 v = make_float4(0.f, 0.f, 0.f, 0.f);
    if (node < N_NODES) {
      if (col < H)
        v = *(const float4*)(mean2 + (size_t)node * H + col);
      else
        v = *(const float4*)(h1 + (size_t)node * H + (col - H));
    }
    *(float4*)(a + idx) = v;
  }
  __syncthreads();

  int cg = t & 31, ng = t >> 5;
  float4 bb = *(const float4*)(b2l + cg * 4);
  float4 acc[8];
#pragma unroll
  for (int n = 0; n < 8; ++n) acc[n] = bb;

  const float4* __restrict__ WcatV = (const float4*)Wcat2;
  const float4* aV = (const float4*)a;
#pragma unroll 4
  for (int k4 = 0; k4 < 64; ++k4) {
    float4 w0 = WcatV[(k4 * 4 + 0) * 32 + cg];
    float4 w1 = WcatV[(k4 * 4 + 1) * 32 + cg];
    float4 w2 = WcatV[(k4 * 4 + 2) * 32 + cg];
    float4 w3 = WcatV[(k4 * 4 + 3) * 32 + cg];
#pragma unroll
    for (int n = 0; n < 8; ++n) {
      float4 av = aV[(ng * 8 + n) * 64 + k4];
      acc[n].x += av.x * w0.x + av.y * w1.x + av.z * w2.x + av.w * w3.x;
      acc[n].y += av.x * w0.y + av.y * w1.y + av.z * w2.y + av.w * w3.y;
      acc[n].z += av.x * w0.z + av.y * w1.z + av.z * w2.z + av.w * w3.z;
      acc[n].w += av.x * w0.w + av.y * w1.w + av.z * w2.w + av.w * w3.w;
    }
  }
  __syncthreads();

#pragma unroll
  for (int n = 0; n < 8; ++n) {
    float4 r;
    r.x = fmaxf(acc[n].x, 0.f);
    r.y = fmaxf(acc[n].y, 0.f);
    r.z = fmaxf(acc[n].z, 0.f);
    r.w = fmaxf(acc[n].w, 0.f);
    *(float4*)(a + (ng * 8 + n) * H + cg * 4) = r;
  }
  __syncthreads();

  if (t < H) {
    int cur = batch[base];
    float s = 0.f;
#pragma unroll 8
    for (int n = 0; n < nvalid; ++n) {
      int g = batch[base + n];
      if (g != cur) {
        atomicAdd(&gsum[cur * H + t], s);
        s = 0.f;
        cur = g;
      }
      s += a[n * H + t];
    }
    atomicAdd(&gsum[cur * H + t], s);
  } else if (t == H) {
    int cur = batch[base];
    float c = 0.f;
    for (int n = 0; n < nvalid; ++n) {
      int g = batch[base + n];
      if (g != cur) {
        atomicAdd(&gcnt[cur], c);
        c = 0.f;
        cur = g;
      }
      c += 1.0f;
    }
    atomicAdd(&gcnt[cur], c);
  }
}

// ---- final: out = (gsum/gcnt) @ Wlin.T + blin ----
__global__ __launch_bounds__(256) void final_lin(
    const float* __restrict__ gsum, const float* __restrict__ gcnt,
    const float* __restrict__ Wlin, const float* __restrict__ blin,
    float* __restrict__ out) {
  int t = blockIdx.x * 256 + threadIdx.x;
  if (t >= G_GRAPHS * OUT_C) return;
  int g = t / OUT_C, o = t - g * OUT_C;
  float inv = 1.0f / fmaxf(gcnt[g], 1.0f);
  float acc = blin[o];
#pragma unroll 16
  for (int k = 0; k < H; ++k)
    acc += (gsum[g * H + k] * inv) * Wlin[o * H + k];
  out[t] = acc;
}

extern "C" void kernel_launch(void* const* d_in, const int* in_sizes, int n_in,
                              void* d_out, int out_size, void* d_ws, size_t ws_size,
                              hipStream_t stream) {
  const float* x    = (const float*)d_in[0];
  const int*   ei   = (const int*)d_in[1];
  const int*   batch= (const int*)d_in[2];
  const float* W1l  = (const float*)d_in[3];
  const float* b1l  = (const float*)d_in[4];
  const float* W1r  = (const float*)d_in[5];
  const float* W2l  = (const float*)d_in[6];
  const float* b2l  = (const float*)d_in[7];
  const float* W2r  = (const float*)d_in[8];
  const float* Wlin = (const float*)d_in[9];
  const float* blin = (const float*)d_in[10];
  float* out = (float*)d_out;

  const int* src = ei;
  const int* dst = ei + N_EDGES;

  // ---- workspace layout (all element counts multiples of 4 for 16B align) ----
  char* wsb = (char*)d_ws;
  int*   ideg   = (int*)wsb;                       // 50000 (zeroed)
  float* gsum   = (float*)(ideg + N_NODES);        // 12800 (zeroed)
  float* gcnt   = gsum + G_GRAPHS * H;             // 100   (zeroed)
  int*   off    = (int*)(gcnt + G_GRAPHS);         // 50004 (padded)
  int*   cursor = off + N_NODES + 4;               // 50000
  int*   ssrc   = cursor + N_NODES;                // 640000
  float* Wcat1  = (float*)(ssrc + N_EDGES);        // 40*128
  float* Wcat2  = Wcat1 + 2 * F_IN * H;            // 256*128
  float* mean1  = Wcat2 + 2 * H * H;               // N*20
  float* h1     = mean1 + (size_t)N_NODES * F_IN;  // N*128
  float* mean2  = h1 + (size_t)N_NODES * H;        // N*128

  size_t zero_bytes = (size_t)(N_NODES + G_GRAPHS * H + G_GRAPHS) * 4;
  hipMemsetAsync(d_ws, 0, zero_bytes, stream);

  build_wcat1<<<2 * F_IN, H, 0, stream>>>(W1l, W1r, Wcat1);
  build_wcat2<<<2 * H, H, 0, stream>>>(W2l, W2r, Wcat2);
  count_deg<<<(N_EDGES + 255) / 256, 256, 0, stream>>>(dst, ideg);
  scan_offsets<<<1, 1024, 0, stream>>>(ideg, off, cursor);
  scatter_edges<<<(N_EDGES + 255) / 256, 256, 0, stream>>>(src, dst, cursor, ssrc);
  csr_agg1<<<(N_NODES + 3) / 4, 256, 0, stream>>>(off, ssrc, x, mean1);
  conv1_tiled<<<(N_NODES + TILE_N - 1) / TILE_N, 256, 0, stream>>>(mean1, x, Wcat1, b1l, h1);
  csr_agg2<<<(N_NODES + 3) / 4, 256, 0, stream>>>(off, ssrc, h1, mean2);
  conv2_pool<<<(N_NODES + TILE_N - 1) / TILE_N, 256, 0, stream>>>(
      h1, mean2, Wcat2, b2l, batch, gsum, gcnt);
  final_lin<<<1, 256, 0, stream>>>(gsum, gcnt, Wlin, blin, out);
}

// Round 4
// 299.293 us; speedup vs baseline: 2.7937x; 1.3417x over previous
//
#include <hip/hip_runtime.h>

#define N_NODES 50000
#define N_EDGES 640000
#define F_IN 20
#define H 128
#define G_GRAPHS 100
#define OUT_C 2
#define TILE_N 64

typedef __attribute__((ext_vector_type(8))) short short8;   // 8 bf16 (4 VGPRs)
typedef __attribute__((ext_vector_type(4))) float f32x4;

__device__ inline ushort f2bf(float f) {  // fp32 -> bf16 RNE
  uint u = __float_as_uint(f);
  return (ushort)((u + 0x7FFFu + ((u >> 16) & 1u)) >> 16);
}

// ---- count in-degree (int) ----
__global__ __launch_bounds__(256) void count_deg(
    const int* __restrict__ dst, int* __restrict__ ideg) {
  int e = blockIdx.x * 256 + threadIdx.x;
  if (e < N_EDGES) atomicAdd(&ideg[dst[e]], 1);
}

// ---- single-block exclusive scan ----
__global__ __launch_bounds__(1024) void scan_offsets(
    const int* __restrict__ ideg, int* __restrict__ off, int* __restrict__ cursor) {
  __shared__ int part[1024];
  int t = threadIdx.x;
  const int CHUNK = (N_NODES + 1023) / 1024;
  int beg = t * CHUNK, end = min(beg + CHUNK, N_NODES);
  int s = 0;
  for (int i = beg; i < end; ++i) s += ideg[i];
  part[t] = s;
  __syncthreads();
  for (int d = 1; d < 1024; d <<= 1) {
    int v = (t >= d) ? part[t - d] : 0;
    __syncthreads();
    part[t] += v;
    __syncthreads();
  }
  int run = (t == 0) ? 0 : part[t - 1];
  for (int i = beg; i < end; ++i) {
    off[i] = run;
    cursor[i] = run;
    run += ideg[i];
  }
  if (t == 1023) off[N_NODES] = run;
}

// ---- scatter edges into dst-sorted order ----
__global__ __launch_bounds__(256) void scatter_edges(
    const int* __restrict__ src, const int* __restrict__ dst,
    int* __restrict__ cursor, int* __restrict__ ssrc) {
  int e = blockIdx.x * 256 + threadIdx.x;
  if (e < N_EDGES) {
    int pos = atomicAdd(&cursor[dst[e]], 1);
    ssrc[pos] = src[e];
  }
}

// ---- hop-1 mean aggregation (fp32, x is small) ----
__global__ __launch_bounds__(256) void csr_agg1(
    const int* __restrict__ off, const int* __restrict__ ssrc,
    const float* __restrict__ x, float* __restrict__ mean1) {
  int node = blockIdx.x * 4 + (threadIdx.x >> 6);
  if (node >= N_NODES) return;
  int lane = threadIdx.x & 63;
  int beg = off[node], end = off[node + 1];
  int j = lane / F_IN;
  int f = lane - j * F_IN;
  float acc = 0.f;
  if (lane < 60) {
    for (int e = beg + j; e < end; e += 3)
      acc += x[(size_t)ssrc[e] * F_IN + f];
  }
  float s = acc + __shfl(acc, lane + 20, 64) + __shfl(acc, lane + 40, 64);
  if (lane < F_IN) {
    float invd = 1.f / fmaxf((float)(end - beg), 1.f);
    mean1[(size_t)node * F_IN + lane] = s * invd;
  }
}

// ---- Wcat1[40][128] fp32: rows 0..19 = W1l.T, rows 20..39 = W1r.T ----
__global__ __launch_bounds__(128) void build_wcat1(
    const float* __restrict__ W1l, const float* __restrict__ W1r,
    float* __restrict__ Wcat1) {
  int k = blockIdx.x;
  int t = threadIdx.x;
  Wcat1[k * H + t] = (k < F_IN) ? W1l[t * F_IN + k] : W1r[t * F_IN + (k - F_IN)];
}

// ---- conv1: register-tiled fp32 GEMM, bf16 output ----
__global__ __launch_bounds__(256) void conv1_tiled(
    const float* __restrict__ mean1, const float* __restrict__ x,
    const float* __restrict__ Wcat1, const float* __restrict__ b1l,
    ushort* __restrict__ h1b) {
  __shared__ float a[TILE_N * 2 * F_IN];
  int t = threadIdx.x;
  int base = blockIdx.x * TILE_N;
#pragma unroll
  for (int j = 0; j < 10; ++j) {
    int idx = j * 256 + t;
    int row = idx / (2 * F_IN);
    int col = idx - row * (2 * F_IN);
    int node = base + row;
    float v = 0.f;
    if (node < N_NODES)
      v = (col < F_IN) ? mean1[(size_t)node * F_IN + col]
                       : x[(size_t)node * F_IN + (col - F_IN)];
    a[idx] = v;
  }
  __syncthreads();
  int cg = t & 31, ng = t >> 5;
  float4 bb = *(const float4*)(b1l + cg * 4);
  float4 acc[8];
#pragma unroll
  for (int n = 0; n < 8; ++n) acc[n] = bb;
  const float4* __restrict__ WV = (const float4*)Wcat1;
#pragma unroll 8
  for (int k = 0; k < 2 * F_IN; ++k) {
    float4 w = WV[k * 32 + cg];
#pragma unroll
    for (int n = 0; n < 8; ++n) {
      float av = a[(ng * 8 + n) * (2 * F_IN) + k];
      acc[n].x += av * w.x;
      acc[n].y += av * w.y;
      acc[n].z += av * w.z;
      acc[n].w += av * w.w;
    }
  }
#pragma unroll
  for (int n = 0; n < 8; ++n) {
    int node = base + ng * 8 + n;
    if (node < N_NODES) {
      ushort4 r;
      r.x = f2bf(fmaxf(acc[n].x, 0.f));
      r.y = f2bf(fmaxf(acc[n].y, 0.f));
      r.z = f2bf(fmaxf(acc[n].z, 0.f));
      r.w = f2bf(fmaxf(acc[n].w, 0.f));
      *(ushort4*)(h1b + (size_t)node * H + cg * 4) = r;
    }
  }
}

// ---- hop-2 mean aggregation: bf16 gather, fp32 accum, bf16 out ----
__global__ __launch_bounds__(256) void csr_agg2(
    const int* __restrict__ off, const int* __restrict__ ssrc,
    const ushort* __restrict__ h1b, ushort* __restrict__ mean2b) {
  int node = blockIdx.x * 4 + (threadIdx.x >> 6);
  if (node >= N_NODES) return;
  int lane = threadIdx.x & 63;
  int beg = off[node], end = off[node + 1];
  const uint* __restrict__ h1u = (const uint*)h1b;  // 64 uints (bf16x2) per row
  float ax = 0.f, ay = 0.f;
  int e = beg;
  for (; e + 3 < end; e += 4) {
    uint v0 = h1u[(size_t)ssrc[e] * 64 + lane];
    uint v1 = h1u[(size_t)ssrc[e + 1] * 64 + lane];
    uint v2 = h1u[(size_t)ssrc[e + 2] * 64 + lane];
    uint v3 = h1u[(size_t)ssrc[e + 3] * 64 + lane];
    ax += __uint_as_float(v0 << 16) + __uint_as_float(v1 << 16) +
          __uint_as_float(v2 << 16) + __uint_as_float(v3 << 16);
    ay += __uint_as_float(v0 & 0xFFFF0000u) + __uint_as_float(v1 & 0xFFFF0000u) +
          __uint_as_float(v2 & 0xFFFF0000u) + __uint_as_float(v3 & 0xFFFF0000u);
  }
  for (; e < end; ++e) {
    uint v = h1u[(size_t)ssrc[e] * 64 + lane];
    ax += __uint_as_float(v << 16);
    ay += __uint_as_float(v & 0xFFFF0000u);
  }
  float invd = 1.f / fmaxf((float)(end - beg), 1.f);
  uint packed = (uint)f2bf(ax * invd) | ((uint)f2bf(ay * invd) << 16);
  ((uint*)mean2b)[(size_t)node * 64 + lane] = packed;
}

// ---- Wb2[128 cols][256 k] bf16: Wb2[col] = concat(W2l[col,:], W2r[col,:]) ----
__global__ __launch_bounds__(256) void build_wb2(
    const float* __restrict__ W2l, const float* __restrict__ W2r,
    ushort* __restrict__ Wb2) {
  int col = blockIdx.x;
  int t = threadIdx.x;  // 0..255 = k
  float v = (t < H) ? W2l[col * H + t] : W2r[col * H + (t - H)];
  Wb2[col * 256 + t] = f2bf(v);
}

// ---- conv2 (MFMA bf16) + relu + pool ----
// C[64][128] = A[64][256] @ W[256][128]; A = [mean2b | h1b]
// 4 waves: wave w owns rows w*16..+15. Per wave: 8 col-tiles x 8 k-steps MFMAs.
__global__ __launch_bounds__(256) void conv2_pool(
    const ushort* __restrict__ h1b, const ushort* __restrict__ mean2b,
    const ushort* __restrict__ Wb2, const float* __restrict__ b2l,
    const int* __restrict__ batch,
    float* __restrict__ gsum, float* __restrict__ gcnt) {
  __shared__ float outt[TILE_N * 129];  // padded stride vs bank conflicts
  int t = threadIdx.x;
  int w = t >> 6, l = t & 63;
  int r0 = l & 15, g = l >> 4;
  int base = blockIdx.x * TILE_N;
  int nvalid = min(TILE_N, N_NODES - base);
  int node = base + w * 16 + r0;          // this lane's A row
  bool rv = node < N_NODES;
  size_t arow = (size_t)(rv ? node : 0) * H;

  f32x4 acc[8];
#pragma unroll
  for (int ct = 0; ct < 8; ++ct) acc[ct] = (f32x4){0.f, 0.f, 0.f, 0.f};
  const short8 zero8 = {0, 0, 0, 0, 0, 0, 0, 0};

#pragma unroll
  for (int ks = 0; ks < 8; ++ks) {
    // A fragment: row = l&15 (within wave's 16), k = ks*32 + g*8 .. +7
    short8 af = zero8;
    if (rv) {
      const ushort* p = (ks < 4) ? (mean2b + arow + ks * 32 + g * 8)
                                 : (h1b + arow + (ks - 4) * 32 + g * 8);
      af = *(const short8*)p;
    }
#pragma unroll
    for (int ct = 0; ct < 8; ++ct) {
      // B fragment: col = ct*16 + (l&15), k = ks*32 + g*8 .. +7 (contiguous in Wb2)
      short8 bf_ = *(const short8*)(Wb2 + (size_t)(ct * 16 + r0) * 256 + ks * 32 + g * 8);
      acc[ct] = __builtin_amdgcn_mfma_f32_16x16x32_bf16(af, bf_, acc[ct], 0, 0, 0);
    }
  }

  // epilogue: C row = (l>>4)*4 + reg, col = ct*16 + (l&15); bias + relu -> LDS
#pragma unroll
  for (int ct = 0; ct < 8; ++ct) {
    int col = ct * 16 + r0;
    float b = b2l[col];
#pragma unroll
    for (int r = 0; r < 4; ++r) {
      int nl = w * 16 + g * 4 + r;
      outt[nl * 129 + col] = fmaxf(acc[ct][r] + b, 0.f);
    }
  }
  __syncthreads();

  // segmented pool over sorted batch ids
  if (t < H) {
    int cur = batch[base];
    float s = 0.f;
#pragma unroll 8
    for (int n = 0; n < nvalid; ++n) {
      int gid = batch[base + n];
      if (gid != cur) {
        atomicAdd(&gsum[cur * H + t], s);
        s = 0.f;
        cur = gid;
      }
      s += outt[n * 129 + t];
    }
    atomicAdd(&gsum[cur * H + t], s);
  } else if (t == H) {
    int cur = batch[base];
    float c = 0.f;
    for (int n = 0; n < nvalid; ++n) {
      int gid = batch[base + n];
      if (gid != cur) {
        atomicAdd(&gcnt[cur], c);
        c = 0.f;
        cur = gid;
      }
      c += 1.0f;
    }
    atomicAdd(&gcnt[cur], c);
  }
}

// ---- final: out = (gsum/gcnt) @ Wlin.T + blin ----
__global__ __launch_bounds__(256) void final_lin(
    const float* __restrict__ gsum, const float* __restrict__ gcnt,
    const float* __restrict__ Wlin, const float* __restrict__ blin,
    float* __restrict__ out) {
  int t = blockIdx.x * 256 + threadIdx.x;
  if (t >= G_GRAPHS * OUT_C) return;
  int g = t / OUT_C, o = t - g * OUT_C;
  float inv = 1.0f / fmaxf(gcnt[g], 1.0f);
  float acc = blin[o];
#pragma unroll 16
  for (int k = 0; k < H; ++k)
    acc += (gsum[g * H + k] * inv) * Wlin[o * H + k];
  out[t] = acc;
}

extern "C" void kernel_launch(void* const* d_in, const int* in_sizes, int n_in,
                              void* d_out, int out_size, void* d_ws, size_t ws_size,
                              hipStream_t stream) {
  const float* x    = (const float*)d_in[0];
  const int*   ei   = (const int*)d_in[1];
  const int*   batch= (const int*)d_in[2];
  const float* W1l  = (const float*)d_in[3];
  const float* b1l  = (const float*)d_in[4];
  const float* W1r  = (const float*)d_in[5];
  const float* W2l  = (const float*)d_in[6];
  const float* b2l  = (const float*)d_in[7];
  const float* W2r  = (const float*)d_in[8];
  const float* Wlin = (const float*)d_in[9];
  const float* blin = (const float*)d_in[10];
  float* out = (float*)d_out;

  const int* src = ei;
  const int* dst = ei + N_EDGES;

  // ---- workspace layout ----
  char* p = (char*)d_ws;
  auto align64 = [](char* q) { return (char*)(((uintptr_t)q + 63) & ~(uintptr_t)63); };
  int* ideg = (int*)p;        p += (size_t)N_NODES * 4;       // zeroed
  float* gsum = (float*)p;    p += (size_t)G_GRAPHS * H * 4;  // zeroed
  float* gcnt = (float*)p;    p += (size_t)G_GRAPHS * 4;      // zeroed
  size_t zero_bytes = (size_t)(p - (char*)d_ws);
  p = align64(p);
  int* off = (int*)p;         p += (size_t)(N_NODES + 4) * 4;
  int* cursor = (int*)p;      p += (size_t)N_NODES * 4;
  int* ssrc = (int*)p;        p += (size_t)N_EDGES * 4;
  float* Wcat1 = (float*)p;   p += (size_t)2 * F_IN * H * 4;
  float* mean1 = (float*)p;   p += (size_t)N_NODES * F_IN * 4;
  p = align64(p);
  ushort* h1b = (ushort*)p;   p += (size_t)N_NODES * H * 2;
  p = align64(p);
  ushort* mean2b = (ushort*)p; p += (size_t)N_NODES * H * 2;
  p = align64(p);
  ushort* Wb2 = (ushort*)p;   p += (size_t)H * 256 * 2;

  hipMemsetAsync(d_ws, 0, zero_bytes, stream);

  build_wcat1<<<2 * F_IN, H, 0, stream>>>(W1l, W1r, Wcat1);
  build_wb2<<<H, 256, 0, stream>>>(W2l, W2r, Wb2);
  count_deg<<<(N_EDGES + 255) / 256, 256, 0, stream>>>(dst, ideg);
  scan_offsets<<<1, 1024, 0, stream>>>(ideg, off, cursor);
  scatter_edges<<<(N_EDGES + 255) / 256, 256, 0, stream>>>(src, dst, cursor, ssrc);
  csr_agg1<<<(N_NODES + 3) / 4, 256, 0, stream>>>(off, ssrc, x, mean1);
  conv1_tiled<<<(N_NODES + TILE_N - 1) / TILE_N, 256, 0, stream>>>(mean1, x, Wcat1, b1l, h1b);
  csr_agg2<<<(N_NODES + 3) / 4, 256, 0, stream>>>(off, ssrc, h1b, mean2b);
  conv2_pool<<<(N_NODES + TILE_N - 1) / TILE_N, 256, 0, stream>>>(
      h1b, mean2b, Wb2, b2l, batch, gsum, gcnt);
  final_lin<<<1, 256, 0, stream>>>(gsum, gcnt, Wlin, blin, out);
}

// Round 5
// 196.434 us; speedup vs baseline: 4.2566x; 1.5236x over previous
//
#include <hip/hip_runtime.h>

#define N_NODES 50000
#define N_EDGES 640000
#define F_IN 20
#define H 128
#define G_GRAPHS 100
#define OUT_C 2
#define TILE_N 64
#define SCAN_BLOCKS 200
#define NODES_PER_SB 250   // SCAN_BLOCKS * NODES_PER_SB == N_NODES

typedef __attribute__((ext_vector_type(8))) short short8;   // 8 bf16 (4 VGPRs)
typedef __attribute__((ext_vector_type(4))) float f32x4;

__device__ inline ushort f2bf(float f) {  // fp32 -> bf16 RNE
  uint u = __float_as_uint(f);
  return (ushort)((u + 0x7FFFu + ((u >> 16) & 1u)) >> 16);
}

// ---- count in-degree (int) ----
__global__ __launch_bounds__(256) void count_deg(
    const int* __restrict__ dst, int* __restrict__ ideg) {
  int e = blockIdx.x * 256 + threadIdx.x;
  if (e < N_EDGES) atomicAdd(&ideg[dst[e]], 1);
}

// ---- hierarchical scan, stage A: per-block degree sums ----
__global__ __launch_bounds__(256) void deg_block_sums(
    const int* __restrict__ ideg, int* __restrict__ blocksum) {
  int b = blockIdx.x, t = threadIdx.x;
  int i = b * NODES_PER_SB + t;
  int v = (t < NODES_PER_SB) ? ideg[i] : 0;
  __shared__ int sm[256];
  sm[t] = v;
  __syncthreads();
#pragma unroll
  for (int d = 128; d > 0; d >>= 1) {
    if (t < d) sm[t] += sm[t + d];
    __syncthreads();
  }
  if (t == 0) blocksum[b] = sm[0];
}

// ---- stage B: exclusive scan of the 200 block sums (one tiny block) ----
__global__ __launch_bounds__(256) void scan_block_sums(
    const int* __restrict__ blocksum, int* __restrict__ blockbase) {
  int t = threadIdx.x;
  __shared__ int sm[256];
  int v = (t < SCAN_BLOCKS) ? blocksum[t] : 0;
  sm[t] = v;
  __syncthreads();
#pragma unroll
  for (int d = 1; d < 256; d <<= 1) {
    int tmp = (t >= d) ? sm[t - d] : 0;
    __syncthreads();
    sm[t] += tmp;
    __syncthreads();
  }
  if (t < SCAN_BLOCKS) blockbase[t] = sm[t] - v;  // exclusive prefix
}

// ---- stage C: block-local exclusive scan + base -> off, cursor ----
__global__ __launch_bounds__(256) void finalize_offsets(
    const int* __restrict__ ideg, const int* __restrict__ blockbase,
    int* __restrict__ off, int* __restrict__ cursor) {
  int b = blockIdx.x, t = threadIdx.x;
  int i = b * NODES_PER_SB + t;
  int v = (t < NODES_PER_SB) ? ideg[i] : 0;
  __shared__ int sm[256];
  sm[t] = v;
  __syncthreads();
#pragma unroll
  for (int d = 1; d < 256; d <<= 1) {
    int tmp = (t >= d) ? sm[t - d] : 0;
    __syncthreads();
    sm[t] += tmp;
    __syncthreads();
  }
  if (t < NODES_PER_SB) {
    int excl = blockbase[b] + sm[t] - v;
    off[i] = excl;
    cursor[i] = excl;
  }
  if (b == 0 && t == 0) off[N_NODES] = N_EDGES;
}

// ---- scatter edges into dst-sorted order ----
__global__ __launch_bounds__(256) void scatter_edges(
    const int* __restrict__ src, const int* __restrict__ dst,
    int* __restrict__ cursor, int* __restrict__ ssrc) {
  int e = blockIdx.x * 256 + threadIdx.x;
  if (e < N_EDGES) {
    int pos = atomicAdd(&cursor[dst[e]], 1);
    ssrc[pos] = src[e];
  }
}

// ---- hop-1 mean aggregation (fp32, x is small) ----
__global__ __launch_bounds__(256) void csr_agg1(
    const int* __restrict__ off, const int* __restrict__ ssrc,
    const float* __restrict__ x, float* __restrict__ mean1) {
  int node = blockIdx.x * 4 + (threadIdx.x >> 6);
  if (node >= N_NODES) return;
  int lane = threadIdx.x & 63;
  int beg = off[node], end = off[node + 1];
  int j = lane / F_IN;
  int f = lane - j * F_IN;
  float acc = 0.f;
  if (lane < 60) {
    for (int e = beg + j; e < end; e += 3)
      acc += x[(size_t)ssrc[e] * F_IN + f];
  }
  float s = acc + __shfl(acc, lane + 20, 64) + __shfl(acc, lane + 40, 64);
  if (lane < F_IN) {
    float invd = 1.f / fmaxf((float)(end - beg), 1.f);
    mean1[(size_t)node * F_IN + lane] = s * invd;
  }
}

// ---- Wcat1[40][128] fp32: rows 0..19 = W1l.T, rows 20..39 = W1r.T ----
__global__ __launch_bounds__(128) void build_wcat1(
    const float* __restrict__ W1l, const float* __restrict__ W1r,
    float* __restrict__ Wcat1) {
  int k = blockIdx.x;
  int t = threadIdx.x;
  Wcat1[k * H + t] = (k < F_IN) ? W1l[t * F_IN + k] : W1r[t * F_IN + (k - F_IN)];
}

// ---- conv1: register-tiled fp32 GEMM, bf16 output ----
__global__ __launch_bounds__(256) void conv1_tiled(
    const float* __restrict__ mean1, const float* __restrict__ x,
    const float* __restrict__ Wcat1, const float* __restrict__ b1l,
    ushort* __restrict__ h1b) {
  __shared__ float a[TILE_N * 2 * F_IN];
  int t = threadIdx.x;
  int base = blockIdx.x * TILE_N;
#pragma unroll
  for (int j = 0; j < 10; ++j) {
    int idx = j * 256 + t;
    int row = idx / (2 * F_IN);
    int col = idx - row * (2 * F_IN);
    int node = base + row;
    float v = 0.f;
    if (node < N_NODES)
      v = (col < F_IN) ? mean1[(size_t)node * F_IN + col]
                       : x[(size_t)node * F_IN + (col - F_IN)];
    a[idx] = v;
  }
  __syncthreads();
  int cg = t & 31, ng = t >> 5;
  float4 bb = *(const float4*)(b1l + cg * 4);
  float4 acc[8];
#pragma unroll
  for (int n = 0; n < 8; ++n) acc[n] = bb;
  const float4* __restrict__ WV = (const float4*)Wcat1;
#pragma unroll 8
  for (int k = 0; k < 2 * F_IN; ++k) {
    float4 w = WV[k * 32 + cg];
#pragma unroll
    for (int n = 0; n < 8; ++n) {
      float av = a[(ng * 8 + n) * (2 * F_IN) + k];
      acc[n].x += av * w.x;
      acc[n].y += av * w.y;
      acc[n].z += av * w.z;
      acc[n].w += av * w.w;
    }
  }
#pragma unroll
  for (int n = 0; n < 8; ++n) {
    int node = base + ng * 8 + n;
    if (node < N_NODES) {
      ushort4 r;
      r.x = f2bf(fmaxf(acc[n].x, 0.f));
      r.y = f2bf(fmaxf(acc[n].y, 0.f));
      r.z = f2bf(fmaxf(acc[n].z, 0.f));
      r.w = f2bf(fmaxf(acc[n].w, 0.f));
      *(ushort4*)(h1b + (size_t)node * H + cg * 4) = r;
    }
  }
}

// ---- hop-2 mean aggregation: bf16 gather, fp32 accum, bf16 out ----
__global__ __launch_bounds__(256) void csr_agg2(
    const int* __restrict__ off, const int* __restrict__ ssrc,
    const ushort* __restrict__ h1b, ushort* __restrict__ mean2b) {
  int node = blockIdx.x * 4 + (threadIdx.x >> 6);
  if (node >= N_NODES) return;
  int lane = threadIdx.x & 63;
  int beg = off[node], end = off[node + 1];
  const uint* __restrict__ h1u = (const uint*)h1b;  // 64 uints (bf16x2) per row
  float ax = 0.f, ay = 0.f;
  int e = beg;
  for (; e + 3 < end; e += 4) {
    uint v0 = h1u[(size_t)ssrc[e] * 64 + lane];
    uint v1 = h1u[(size_t)ssrc[e + 1] * 64 + lane];
    uint v2 = h1u[(size_t)ssrc[e + 2] * 64 + lane];
    uint v3 = h1u[(size_t)ssrc[e + 3] * 64 + lane];
    ax += __uint_as_float(v0 << 16) + __uint_as_float(v1 << 16) +
          __uint_as_float(v2 << 16) + __uint_as_float(v3 << 16);
    ay += __uint_as_float(v0 & 0xFFFF0000u) + __uint_as_float(v1 & 0xFFFF0000u) +
          __uint_as_float(v2 & 0xFFFF0000u) + __uint_as_float(v3 & 0xFFFF0000u);
  }
  for (; e < end; ++e) {
    uint v = h1u[(size_t)ssrc[e] * 64 + lane];
    ax += __uint_as_float(v << 16);
    ay += __uint_as_float(v & 0xFFFF0000u);
  }
  float invd = 1.f / fmaxf((float)(end - beg), 1.f);
  uint packed = (uint)f2bf(ax * invd) | ((uint)f2bf(ay * invd) << 16);
  ((uint*)mean2b)[(size_t)node * 64 + lane] = packed;
}

// ---- Wb2[128 cols][256 k] bf16: Wb2[col] = concat(W2l[col,:], W2r[col,:]) ----
__global__ __launch_bounds__(256) void build_wb2(
    const float* __restrict__ W2l, const float* __restrict__ W2r,
    ushort* __restrict__ Wb2) {
  int col = blockIdx.x;
  int t = threadIdx.x;  // 0..255 = k
  float v = (t < H) ? W2l[col * H + t] : W2r[col * H + (t - H)];
  Wb2[col * 256 + t] = f2bf(v);
}

// ---- conv2 (MFMA bf16) + relu + pool ----
// C[64][128] = A[64][256] @ W[256][128]; A = [mean2b | h1b]
__global__ __launch_bounds__(256) void conv2_pool(
    const ushort* __restrict__ h1b, const ushort* __restrict__ mean2b,
    const ushort* __restrict__ Wb2, const float* __restrict__ b2l,
    const int* __restrict__ batch,
    float* __restrict__ gsum, float* __restrict__ gcnt) {
  __shared__ float outt[TILE_N * 129];  // padded stride vs bank conflicts
  int t = threadIdx.x;
  int w = t >> 6, l = t & 63;
  int r0 = l & 15, g = l >> 4;
  int base = blockIdx.x * TILE_N;
  int nvalid = min(TILE_N, N_NODES - base);
  int node = base + w * 16 + r0;          // this lane's A row
  bool rv = node < N_NODES;
  size_t arow = (size_t)(rv ? node : 0) * H;

  f32x4 acc[8];
#pragma unroll
  for (int ct = 0; ct < 8; ++ct) acc[ct] = (f32x4){0.f, 0.f, 0.f, 0.f};
  const short8 zero8 = {0, 0, 0, 0, 0, 0, 0, 0};

#pragma unroll
  for (int ks = 0; ks < 8; ++ks) {
    short8 af = zero8;
    if (rv) {
      const ushort* p = (ks < 4) ? (mean2b + arow + ks * 32 + g * 8)
                                 : (h1b + arow + (ks - 4) * 32 + g * 8);
      af = *(const short8*)p;
    }
#pragma unroll
    for (int ct = 0; ct < 8; ++ct) {
      short8 bf_ = *(const short8*)(Wb2 + (size_t)(ct * 16 + r0) * 256 + ks * 32 + g * 8);
      acc[ct] = __builtin_amdgcn_mfma_f32_16x16x32_bf16(af, bf_, acc[ct], 0, 0, 0);
    }
  }

#pragma unroll
  for (int ct = 0; ct < 8; ++ct) {
    int col = ct * 16 + r0;
    float b = b2l[col];
#pragma unroll
    for (int r = 0; r < 4; ++r) {
      int nl = w * 16 + g * 4 + r;
      outt[nl * 129 + col] = fmaxf(acc[ct][r] + b, 0.f);
    }
  }
  __syncthreads();

  if (t < H) {
    int cur = batch[base];
    float s = 0.f;
#pragma unroll 8
    for (int n = 0; n < nvalid; ++n) {
      int gid = batch[base + n];
      if (gid != cur) {
        atomicAdd(&gsum[cur * H + t], s);
        s = 0.f;
        cur = gid;
      }
      s += outt[n * 129 + t];
    }
    atomicAdd(&gsum[cur * H + t], s);
  } else if (t == H) {
    int cur = batch[base];
    float c = 0.f;
    for (int n = 0; n < nvalid; ++n) {
      int gid = batch[base + n];
      if (gid != cur) {
        atomicAdd(&gcnt[cur], c);
        c = 0.f;
        cur = gid;
      }
      c += 1.0f;
    }
    atomicAdd(&gcnt[cur], c);
  }
}

// ---- final: out = (gsum/gcnt) @ Wlin.T + blin ----
__global__ __launch_bounds__(256) void final_lin(
    const float* __restrict__ gsum, const float* __restrict__ gcnt,
    const float* __restrict__ Wlin, const float* __restrict__ blin,
    float* __restrict__ out) {
  int t = blockIdx.x * 256 + threadIdx.x;
  if (t >= G_GRAPHS * OUT_C) return;
  int g = t / OUT_C, o = t - g * OUT_C;
  float inv = 1.0f / fmaxf(gcnt[g], 1.0f);
  float acc = blin[o];
#pragma unroll 16
  for (int k = 0; k < H; ++k)
    acc += (gsum[g * H + k] * inv) * Wlin[o * H + k];
  out[t] = acc;
}

extern "C" void kernel_launch(void* const* d_in, const int* in_sizes, int n_in,
                              void* d_out, int out_size, void* d_ws, size_t ws_size,
                              hipStream_t stream) {
  const float* x    = (const float*)d_in[0];
  const int*   ei   = (const int*)d_in[1];
  const int*   batch= (const int*)d_in[2];
  const float* W1l  = (const float*)d_in[3];
  const float* b1l  = (const float*)d_in[4];
  const float* W1r  = (const float*)d_in[5];
  const float* W2l  = (const float*)d_in[6];
  const float* b2l  = (const float*)d_in[7];
  const float* W2r  = (const float*)d_in[8];
  const float* Wlin = (const float*)d_in[9];
  const float* blin = (const float*)d_in[10];
  float* out = (float*)d_out;

  const int* src = ei;
  const int* dst = ei + N_EDGES;

  // ---- workspace layout ----
  char* p = (char*)d_ws;
  auto align64 = [](char* q) { return (char*)(((uintptr_t)q + 63) & ~(uintptr_t)63); };
  int* ideg = (int*)p;        p += (size_t)N_NODES * 4;       // zeroed
  float* gsum = (float*)p;    p += (size_t)G_GRAPHS * H * 4;  // zeroed
  float* gcnt = (float*)p;    p += (size_t)G_GRAPHS * 4;      // zeroed
  size_t zero_bytes = (size_t)(p - (char*)d_ws);
  p = align64(p);
  int* off = (int*)p;         p += (size_t)(N_NODES + 4) * 4;
  int* cursor = (int*)p;      p += (size_t)N_NODES * 4;
  int* ssrc = (int*)p;        p += (size_t)N_EDGES * 4;
  int* blocksum = (int*)p;    p += (size_t)SCAN_BLOCKS * 4;
  int* blockbase = (int*)p;   p += (size_t)SCAN_BLOCKS * 4;
  float* Wcat1 = (float*)p;   p += (size_t)2 * F_IN * H * 4;
  float* mean1 = (float*)p;   p += (size_t)N_NODES * F_IN * 4;
  p = align64(p);
  ushort* h1b = (ushort*)p;   p += (size_t)N_NODES * H * 2;
  p = align64(p);
  ushort* mean2b = (ushort*)p; p += (size_t)N_NODES * H * 2;
  p = align64(p);
  ushort* Wb2 = (ushort*)p;   p += (size_t)H * 256 * 2;

  hipMemsetAsync(d_ws, 0, zero_bytes, stream);

  build_wcat1<<<2 * F_IN, H, 0, stream>>>(W1l, W1r, Wcat1);
  build_wb2<<<H, 256, 0, stream>>>(W2l, W2r, Wb2);
  count_deg<<<(N_EDGES + 255) / 256, 256, 0, stream>>>(dst, ideg);
  deg_block_sums<<<SCAN_BLOCKS, 256, 0, stream>>>(ideg, blocksum);
  scan_block_sums<<<1, 256, 0, stream>>>(blocksum, blockbase);
  finalize_offsets<<<SCAN_BLOCKS, 256, 0, stream>>>(ideg, blockbase, off, cursor);
  scatter_edges<<<(N_EDGES + 255) / 256, 256, 0, stream>>>(src, dst, cursor, ssrc);
  csr_agg1<<<(N_NODES + 3) / 4, 256, 0, stream>>>(off, ssrc, x, mean1);
  conv1_tiled<<<(N_NODES + TILE_N - 1) / TILE_N, 256, 0, stream>>>(mean1, x, Wcat1, b1l, h1b);
  csr_agg2<<<(N_NODES + 3) / 4, 256, 0, stream>>>(off, ssrc, h1b, mean2b);
  conv2_pool<<<(N_NODES + TILE_N - 1) / TILE_N, 256, 0, stream>>>(
      h1b, mean2b, Wb2, b2l, batch, gsum, gcnt);
  final_lin<<<1, 256, 0, stream>>>(gsum, gcnt, Wlin, blin, out);
}